// Round 11
// baseline (321.335 us; speedup 1.0000x reference)
//
#include <hip/hip_runtime.h>
#include <hip/hip_bf16.h>
#include <stdint.h>

#define T_SEQ 4096
#define HIDDEN 2048
#define NQH 32
#define NKVH 8
#define DH 128
#define DVH 96
#define WWIN 512
#define QKVN 5888           // 32*128 + 8*128 + 8*96
#define KOFF 4096
#define VOFF 5120
#define ATTN 3072           // 32*96
#define QSCALE 0.08838834764831845f  // 128^-0.5

typedef uint16_t u16;
typedef uint32_t u32;
typedef __bf16 bfrag8 __attribute__((ext_vector_type(8)));
typedef float f32x4v __attribute__((ext_vector_type(4)));
typedef float f32x16 __attribute__((ext_vector_type(16)));

__device__ __forceinline__ u16 f2bf(float x) {
  u32 u = __float_as_uint(x);
  return (u16)((u + 0x7fffu + ((u >> 16) & 1u)) >> 16);
}
__device__ __forceinline__ float bf2f(u16 v) { return __uint_as_float(((u32)v) << 16); }

__device__ __forceinline__ void gload16(const u16* src, char* ldst) {
  __builtin_amdgcn_global_load_lds((const __attribute__((address_space(1))) u32*)src,
                                   (__attribute__((address_space(3))) u32*)ldst, 16, 0, 0);
}

// ---------------- merged f32 -> bf16 convert (3 buffers, 1 launch) --------
__global__ void cvt3_kernel(const float* __restrict__ i1, const float* __restrict__ i2,
                            const float* __restrict__ i3,
                            u16* __restrict__ o1, u16* __restrict__ o2, u16* __restrict__ o3,
                            int n1, int n2, int n3) {
  int i = blockIdx.x * blockDim.x + threadIdx.x;
  int st = gridDim.x * blockDim.x;
  int total = n1 + n2 + n3;
  for (; i < total; i += st) {
    const float4* src;
    ushort4* dst;
    int j;
    if (i < n1) { src = (const float4*)i1; dst = (ushort4*)o1; j = i; }
    else if (i < n1 + n2) { src = (const float4*)i2; dst = (ushort4*)o2; j = i - n1; }
    else { src = (const float4*)i3; dst = (ushort4*)o3; j = i - n1 - n2; }
    float4 v = src[j];
    ushort4 o;
    o.x = f2bf(v.x); o.y = f2bf(v.y); o.z = f2bf(v.z); o.w = f2bf(v.w);
    dst[j] = o;
  }
}

// =======================================================================
// GEMM v3k32: v3 geometry with BK=32 and 3x24KB LDS -> 2 blocks/CU (TLP).
// BM=256 BN=128, 8 waves 4Mx2N (64x64/wave), 32x32x16 MFMA.
// Same sync proof as v3: stage(t+1) 3 loads -> vmcnt(3) -> barrier;
// triple buffer makes pre-barrier staging race-free. Rows now 64 B,
// swizzle key (row&3)<<4 over the 4 16B slots (same involution on both
// staging-source and read sides).
// =======================================================================
template<int OUT_F32>
__global__ __launch_bounds__(512, 4) void gemm_v3k32(const u16* __restrict__ A,
                                                     const u16* __restrict__ B,
                                                     void* __restrict__ Cp,
                                                     int M, int N, int K, int nbm) {
  extern __shared__ char lds[];   // 3 x 24576 B
  const int tid = threadIdx.x;
  const int w = tid >> 6, lane = tid & 63;
  const int wr = w >> 1, wc = w & 1;
  const int r5 = lane & 31, kg = lane >> 5;

  const int nwg = gridDim.x;
  int bid = (int)blockIdx.x;
  if ((nwg & 7) == 0) bid = (bid & 7) * (nwg >> 3) + (bid >> 3);
  const int bm = (bid % nbm) * 256;
  const int bn = (bid / nbm) * 128;
  const int NT = K >> 5;

  f32x16 acc[2][2];
#pragma unroll
  for (int mb = 0; mb < 2; mb++)
#pragma unroll
    for (int nb = 0; nb < 2; nb++)
#pragma unroll
      for (int i = 0; i < 16; i++) acc[mb][nb][i] = 0.f;

  // read addr: q ^ (ks<<5); physical slot = logical slot ^ (row&3)
  const int q = r5 * 64 + ((kg ^ (r5 & 3)) << 4);

  auto stage = [&](int t) {
    char* dst = lds + (t % 3) * 24576;
    const u16* Abase = A + (size_t)bm * K + ((size_t)t << 5);
    const u16* Bbase = B + (size_t)bn * K + ((size_t)t << 5);
#pragma unroll
    for (int i = 0; i < 2; i++) {      // A: 256x32x2B = 16 KB
      int D = (i * 512 + tid) * 16;
      int row = D >> 6;
      int kb = (D ^ ((row & 3) << 4)) & 63;
      gload16(Abase + (size_t)row * K + (kb >> 1), dst + D);
    }
    {                                   // B: 128x32x2B = 8 KB
      int D = tid * 16;
      int row = D >> 6;
      int kb = (D ^ ((row & 3) << 4)) & 63;
      gload16(Bbase + (size_t)row * K + (kb >> 1), dst + 16384 + D);
    }
  };

  stage(0);

  for (int t = 0; t < NT; ++t) {
    const char* Ab = lds + (t % 3) * 24576 + wr * 4096;
    const char* Bb = lds + (t % 3) * 24576 + 16384 + wc * 4096;
    if (t + 1 < NT) {
      stage(t + 1);
      asm volatile("s_waitcnt vmcnt(3)");
    } else {
      asm volatile("s_waitcnt vmcnt(0)");
    }
    asm volatile("s_barrier" ::: "memory");

    bfrag8 af[2][2], bf[2][2];
#pragma unroll
    for (int ks = 0; ks < 2; ks++) {
#pragma unroll
      for (int mb = 0; mb < 2; mb++)
        af[mb][ks] = *(const bfrag8*)(Ab + mb * 2048 + (q ^ (ks << 5)));
#pragma unroll
      for (int nb = 0; nb < 2; nb++)
        bf[nb][ks] = *(const bfrag8*)(Bb + nb * 2048 + (q ^ (ks << 5)));
    }
    __builtin_amdgcn_s_setprio(1);
#pragma unroll
    for (int ks = 0; ks < 2; ks++)
#pragma unroll
      for (int mb = 0; mb < 2; mb++)
#pragma unroll
        for (int nb = 0; nb < 2; nb++)
          acc[mb][nb] = __builtin_amdgcn_mfma_f32_32x32x16_bf16(af[mb][ks], bf[nb][ks], acc[mb][nb], 0, 0, 0);
    __builtin_amdgcn_s_setprio(0);
  }

  const int rb0 = bm + wr * 64;
  const int cb0 = bn + wc * 64;
#pragma unroll
  for (int mb = 0; mb < 2; mb++)
#pragma unroll
    for (int nb = 0; nb < 2; nb++)
#pragma unroll
      for (int i = 0; i < 16; i++) {
        int rowl = (i & 3) + 8 * (i >> 2) + 4 * kg;
        size_t off = (size_t)(rb0 + mb * 32 + rowl) * N + cb0 + nb * 32 + r5;
        if (OUT_F32) ((float*)Cp)[off] = acc[mb][nb][i];
        else         ((u16*)Cp)[off] = f2bf(acc[mb][nb][i]);
      }
}

// =======================================================================
// GEMM core v3 (round-5 proven, BK=64): used for gemm2
// =======================================================================
template<int OUT_F32>
__global__ __launch_bounds__(512, 2) void gemm_v3(const u16* __restrict__ A,
                                                  const u16* __restrict__ B,
                                                  void* __restrict__ Cp,
                                                  int M, int N, int K, int nbm) {
  extern __shared__ char lds[];   // 3 x 49152 B
  const int tid = threadIdx.x;
  const int w = tid >> 6, lane = tid & 63;
  const int wr = w >> 1, wc = w & 1;
  const int r5 = lane & 31, kg = lane >> 5;

  const int nwg = gridDim.x;
  int bid = (int)blockIdx.x;
  if ((nwg & 7) == 0) bid = (bid & 7) * (nwg >> 3) + (bid >> 3);
  const int bm = (bid % nbm) * 256;
  const int bn = (bid / nbm) * 128;
  const int NT = K >> 6;

  f32x16 acc[2][2];
#pragma unroll
  for (int mb = 0; mb < 2; mb++)
#pragma unroll
    for (int nb = 0; nb < 2; nb++)
#pragma unroll
      for (int i = 0; i < 16; i++) acc[mb][nb][i] = 0.f;

  const int q = r5 * 128 + ((kg ^ (r5 & 7)) << 4);

  auto stageA = [&](int t) {
    char* dst = lds + (t % 3) * 49152;
    const u16* Abase = A + (size_t)bm * K + ((size_t)t << 6);
#pragma unroll
    for (int i = 0; i < 4; i++) {
      int D = (w * 4 + i) * 1024 + lane * 16;
      int row = D >> 7;
      int kb = (D ^ ((row & 7) << 4)) & 127;
      gload16(Abase + (size_t)row * K + (kb >> 1), dst + D);
    }
  };
  auto stageB = [&](int t) {
    char* dst = lds + (t % 3) * 49152 + 32768;
    const u16* Bbase = B + (size_t)bn * K + ((size_t)t << 6);
#pragma unroll
    for (int i = 0; i < 2; i++) {
      int D = (w * 2 + i) * 1024 + lane * 16;
      int row = D >> 7;
      int kb = (D ^ ((row & 7) << 4)) & 127;
      gload16(Bbase + (size_t)row * K + (kb >> 1), dst + D);
    }
  };

  stageA(0); stageB(0);

  for (int t = 0; t < NT; ++t) {
    const char* Ab = lds + (t % 3) * 49152 + wr * 8192;
    const char* Bb = lds + (t % 3) * 49152 + 32768 + wc * 8192;
    if (t + 1 < NT) {
      stageA(t + 1);
      stageB(t + 1);
      asm volatile("s_waitcnt vmcnt(6)");
    } else {
      asm volatile("s_waitcnt vmcnt(0)");
    }
    asm volatile("s_barrier" ::: "memory");

    bfrag8 af[2][2], bf[2][2];
#pragma unroll
    for (int ks = 0; ks < 2; ks++) {
#pragma unroll
      for (int mb = 0; mb < 2; mb++)
        af[mb][ks] = *(const bfrag8*)(Ab + mb * 4096 + (q ^ (ks << 5)));
#pragma unroll
      for (int nb = 0; nb < 2; nb++)
        bf[nb][ks] = *(const bfrag8*)(Bb + nb * 4096 + (q ^ (ks << 5)));
    }
    __builtin_amdgcn_s_setprio(1);
#pragma unroll
    for (int ks = 0; ks < 2; ks++)
#pragma unroll
      for (int mb = 0; mb < 2; mb++)
#pragma unroll
        for (int nb = 0; nb < 2; nb++)
          acc[mb][nb] = __builtin_amdgcn_mfma_f32_32x32x16_bf16(af[mb][ks], bf[nb][ks], acc[mb][nb], 0, 0, 0);
    __builtin_amdgcn_s_setprio(0);

    bfrag8 af2[2][2], bf2[2][2];
#pragma unroll
    for (int ks = 0; ks < 2; ks++) {
#pragma unroll
      for (int mb = 0; mb < 2; mb++)
        af2[mb][ks] = *(const bfrag8*)(Ab + mb * 4096 + (q ^ ((ks + 2) << 5)));
#pragma unroll
      for (int nb = 0; nb < 2; nb++)
        bf2[nb][ks] = *(const bfrag8*)(Bb + nb * 4096 + (q ^ ((ks + 2) << 5)));
    }
    __builtin_amdgcn_s_setprio(1);
#pragma unroll
    for (int ks = 0; ks < 2; ks++)
#pragma unroll
      for (int mb = 0; mb < 2; mb++)
#pragma unroll
        for (int nb = 0; nb < 2; nb++)
          acc[mb][nb] = __builtin_amdgcn_mfma_f32_32x32x16_bf16(af2[mb][ks], bf2[nb][ks], acc[mb][nb], 0, 0, 0);
    __builtin_amdgcn_s_setprio(0);
  }

  const int rb0 = bm + wr * 64;
  const int cb0 = bn + wc * 64;
#pragma unroll
  for (int mb = 0; mb < 2; mb++)
#pragma unroll
    for (int nb = 0; nb < 2; nb++)
#pragma unroll
      for (int i = 0; i < 16; i++) {
        int rowl = (i & 3) + 8 * (i >> 2) + 4 * kg;
        size_t off = (size_t)(rb0 + mb * 32 + rowl) * N + cb0 + nb * 32 + r5;
        if (OUT_F32) ((float*)Cp)[off] = acc[mb][nb][i];
        else         ((u16*)Cp)[off] = f2bf(acc[mb][nb][i]);
      }
}

// ---------------- fallback bf16 NT GEMM (round-2 proven) ----------------
template<int OUT_F32>
__global__ __launch_bounds__(256) void gemm_nt(const u16* __restrict__ A,
                                               const u16* __restrict__ B,
                                               void* __restrict__ Cp,
                                               int M, int N, int K) {
  __shared__ u16 Asm[128 * 32];
  __shared__ u16 Bsm[128 * 32];
  const int tid = threadIdx.x;
  const int wv = tid >> 6, lane = tid & 63;
  const int bm = blockIdx.x * 128, bn = blockIdx.y * 128;
  const int wm = (wv >> 1) * 64, wn = (wv & 1) * 64;
  const int srow = lane >> 2;
  const int scol = (lane & 3) * 8;
  const int fr = lane & 15, fk = (lane >> 4) * 8;
  f32x4v acc[4][4];
#pragma unroll
  for (int i = 0; i < 4; i++)
#pragma unroll
    for (int j = 0; j < 4; j++) acc[i][j] = {0.f, 0.f, 0.f, 0.f};

  for (int kt = 0; kt < K; kt += 32) {
    __syncthreads();
#pragma unroll
    for (int c = 0; c < 2; c++) {
      const int ci = wv * 2 + c;
      const u16* ga = A + (size_t)(bm + ci * 16 + srow) * K + kt + scol;
      const u16* gb = B + (size_t)(bn + ci * 16 + srow) * K + kt + scol;
      gload16(ga, (char*)(Asm + ci * 512));
      gload16(gb, (char*)(Bsm + ci * 512));
    }
    __syncthreads();
    bfrag8 af[4], bf[4];
#pragma unroll
    for (int i = 0; i < 4; i++) af[i] = *(const bfrag8*)(Asm + (wm + i * 16 + fr) * 32 + fk);
#pragma unroll
    for (int j = 0; j < 4; j++) bf[j] = *(const bfrag8*)(Bsm + (wn + j * 16 + fr) * 32 + fk);
#pragma unroll
    for (int i = 0; i < 4; i++)
#pragma unroll
      for (int j = 0; j < 4; j++)
        acc[i][j] = __builtin_amdgcn_mfma_f32_16x16x32_bf16(af[i], bf[j], acc[i][j], 0, 0, 0);
  }
  const int orow = (lane >> 4) * 4, ocol = lane & 15;
#pragma unroll
  for (int i = 0; i < 4; i++)
#pragma unroll
    for (int j = 0; j < 4; j++) {
      size_t base = (size_t)(bm + wm + i * 16 + orow) * N + (size_t)(bn + wn + j * 16 + ocol);
#pragma unroll
      for (int r = 0; r < 4; r++) {
        if (OUT_F32) ((float*)Cp)[base + (size_t)r * N] = acc[i][j][r];
        else         ((u16*)Cp)[base + (size_t)r * N] = f2bf(acc[i][j][r]);
      }
    }
}

// ---------------- RoPE in-place on q,k — uint4-vectorized (8 d/thread) ----
__global__ void rope_kernel(u16* __restrict__ qkv, const int* __restrict__ pos) {
  int gid = blockIdx.x * 256 + threadIdx.x;   // 4096*40*8 threads
  int dc = gid & 7;
  int r = gid >> 3;
  int hh = r % 40;
  int t = r / 40;
  if (t >= T_SEQ) return;
  int off = (hh < 32) ? hh * 128 : KOFF + (hh - 32) * 128;
  u16* p = qkv + (size_t)t * QKVN + off + dc * 8;
  uint4 a = *(const uint4*)p;
  uint4 b = *(const uint4*)(p + 64);
  const u32* aw = (const u32*)&a;
  const u32* bw = (const u32*)&b;
  float pt = (float)pos[t];
  float sc = (hh < 32) ? QSCALE : 1.0f;
  union { uint4 v; u16 s[8]; } ra, rb;
#pragma unroll
  for (int j = 0; j < 8; j++) {
    int d = dc * 8 + j;
    float inv_freq = exp2f(-(float)d * 0.3114307588956852f);
    float ang = pt * inv_freq;
    float cs = cosf(ang), sn = sinf(ang);
    float x1 = bf2f((u16)(aw[j >> 1] >> ((j & 1) * 16)));
    float x2 = bf2f((u16)(bw[j >> 1] >> ((j & 1) * 16)));
    ra.s[j] = f2bf((x1 * cs - x2 * sn) * sc);
    rb.s[j] = f2bf((x2 * cs + x1 * sn) * sc);
  }
  *(uint4*)p = ra.v;
  *(uint4*)(p + 64) = rb.v;
}

// ---------------- V transpose: qkv V region -> vt[hk][dv][t] ----------------
__global__ __launch_bounds__(256) void vt_kernel(const u16* __restrict__ qkv,
                                                 u16* __restrict__ vt) {
  __shared__ u16 tile[64][100];
  const int t0 = blockIdx.x * 64;
  const int hk = blockIdx.y;
  const int tid = threadIdx.x;
#pragma unroll
  for (int i = 0; i < 3; i++) {
    int idx = i * 256 + tid;
    int row = idx / 12, ch = idx % 12;
    const u16* g = qkv + (size_t)(t0 + row) * QKVN + VOFF + hk * DVH + ch * 8;
    uint2 a = *(const uint2*)g;
    uint2 b = *(const uint2*)(g + 4);
    *(uint2*)&tile[row][ch * 8] = a;
    *(uint2*)&tile[row][ch * 8 + 4] = b;
  }
  __syncthreads();
#pragma unroll
  for (int i = 0; i < 3; i++) {
    int idx = i * 256 + tid;
    int dv = idx >> 3, tc = (idx & 7) * 8;
    union { uint4 v4; u16 s[8]; } o;
#pragma unroll
    for (int j = 0; j < 8; j++) o.s[j] = tile[tc + j][dv];
    *(uint4*)(vt + (((size_t)(hk * 96 + dv)) << 12) + t0 + tc) = o.v4;
  }
}

// ---------------- MFMA sliding-window attention with sink (r10 proven) ----
__global__ __launch_bounds__(256, 2) void attn_mfma(const u16* __restrict__ qkv,
                                                    const u16* __restrict__ vt,
                                                    const float* __restrict__ sink_bias,
                                                    u16* __restrict__ attn_out) {
  extern __shared__ char smem[];

  const int tid = threadIdx.x;
  const int wv = tid >> 6;
  const int lane = tid & 63;
  const int g = lane >> 4;
  const int c = lane & 15;
  const int t0 = blockIdx.x * 32;
  const int hk = blockIdx.y;
  const int h = hk * 4 + wv;
  u16* pw = (u16*)(smem + 57344 + wv * 4096);

  bfrag8 qf[2][4];
#pragma unroll
  for (int m = 0; m < 2; m++)
#pragma unroll
    for (int kf = 0; kf < 4; kf++)
      qf[m][kf] = *(const bfrag8*)(qkv + (size_t)(t0 + m * 16 + c) * QKVN + h * DH + kf * 32 + g * 8);

  f32x4v acc_o[2][6];
#pragma unroll
  for (int m = 0; m < 2; m++)
#pragma unroll
    for (int n = 0; n < 6; n++) acc_o[m][n] = {0.f, 0.f, 0.f, 0.f};

  const float sb = sink_bias[h];
  float m_run[2][4], l_run[2][4];
#pragma unroll
  for (int m = 0; m < 2; m++)
#pragma unroll
    for (int r = 0; r < 4; r++) { m_run[m][r] = sb; l_run[m][r] = 1.0f; }

  int cb0 = t0 - (WWIN - 1);
  cb0 = (cb0 < 0) ? 0 : (cb0 & ~63);
  const int nc = (t0 + 32 - cb0 + 63) >> 6;

  auto stage = [&](int ci) {
    const int cb = cb0 + ci * 64;
    char* kd = smem + (ci & 1) * 16384;
    char* vd = smem + 32768 + (ci & 1) * 12288;
#pragma unroll
    for (int it = 0; it < 4; it++) {
      int dest = it * 4096 + tid * 16;
      int row = dest >> 8;
      int src = dest ^ ((row & 7) << 4);
      gload16(qkv + (size_t)(cb + row) * QKVN + KOFF + hk * DH + ((src & 255) >> 1), kd + dest);
    }
#pragma unroll
    for (int it = 0; it < 3; it++) {
      int dest = it * 4096 + tid * 16;
      int row = dest >> 7;
      int src = dest ^ ((row & 7) << 4);
      gload16(vt + (((size_t)(hk * 96 + row)) << 12) + cb + ((src & 127) >> 1), vd + dest);
    }
  };

  stage(0);
  if (nc > 1) stage(1);

  for (int ci = 0; ci < nc; ci++) {
    const int cb = cb0 + ci * 64;
    const char* k_lds = smem + (ci & 1) * 16384;
    const char* v_lds = smem + 32768 + (ci & 1) * 12288;
    if (ci + 1 < nc) asm volatile("s_waitcnt vmcnt(7)");
    else             asm volatile("s_waitcnt vmcnt(0)");
    asm volatile("s_barrier" ::: "memory");

    f32x4v s[2][4];
#pragma unroll
    for (int m = 0; m < 2; m++)
#pragma unroll
      for (int n = 0; n < 4; n++) s[m][n] = {0.f, 0.f, 0.f, 0.f};
#pragma unroll
    for (int kf = 0; kf < 4; kf++) {
      bfrag8 kb[4];
#pragma unroll
      for (int n = 0; n < 4; n++) {
        int key = n * 16 + c;
        int byt = ((key << 8) + (kf << 6) + (g << 4)) ^ ((key & 7) << 4);
        kb[n] = *(const bfrag8*)(k_lds + byt);
      }
#pragma unroll
      for (int m = 0; m < 2; m++)
#pragma unroll
        for (int n = 0; n < 4; n++)
          s[m][n] = __builtin_amdgcn_mfma_f32_16x16x32_bf16(qf[m][kf], kb[n], s[m][n], 0, 0, 0);
    }

    if ((cb + 63 > t0) || (cb + WWIN < t0 + 32)) {
#pragma unroll
      for (int m = 0; m < 2; m++)
#pragma unroll
        for (int n = 0; n < 4; n++)
#pragma unroll
          for (int r = 0; r < 4; r++) {
            int rel = (t0 + m * 16 + g * 4 + r) - (cb + n * 16 + c);
            if (!(rel >= 0 && rel < WWIN)) s[m][n][r] = -3.0e38f;
          }
    }

    float corr[2][4];
    bool grew = false;
#pragma unroll
    for (int m = 0; m < 2; m++)
#pragma unroll
      for (int r = 0; r < 4; r++) {
        float v0 = fmaxf(fmaxf(s[m][0][r], s[m][1][r]), fmaxf(s[m][2][r], s[m][3][r]));
        v0 = fmaxf(v0, __shfl_xor(v0, 1));
        v0 = fmaxf(v0, __shfl_xor(v0, 2));
        v0 = fmaxf(v0, __shfl_xor(v0, 4));
        v0 = fmaxf(v0, __shfl_xor(v0, 8));
        float mo = m_run[m][r];
        float mn = fmaxf(mo, v0);
        corr[m][r] = __expf(mo - mn);
        grew |= (mn > mo);
        m_run[m][r] = mn;
        float p0 = __expf(s[m][0][r] - mn);
        float p1 = __expf(s[m][1][r] - mn);
        float p2 = __expf(s[m][2][r] - mn);
        float p3 = __expf(s[m][3][r] - mn);
        s[m][0][r] = p0; s[m][1][r] = p1; s[m][2][r] = p2; s[m][3][r] = p3;
        float rs = p0 + p1 + p2 + p3;
        rs += __shfl_xor(rs, 1);
        rs += __shfl_xor(rs, 2);
        rs += __shfl_xor(rs, 4);
        rs += __shfl_xor(rs, 8);
        l_run[m][r] = l_run[m][r] * corr[m][r] + rs;
      }
    if (__any(grew)) {   // exact: when corr==1 for all rows the rescale is a no-op
#pragma unroll
      for (int m = 0; m < 2; m++)
#pragma unroll
        for (int n = 0; n < 6; n++)
#pragma unroll
        for (int r = 0; r < 4; r++) acc_o[m][n][r] *= corr[m][r];
    }

#pragma unroll
    for (int m = 0; m < 2; m++)
#pragma unroll
      for (int n = 0; n < 4; n++) {
        u32 lo = (u32)f2bf(s[m][n][0]) | ((u32)f2bf(s[m][n][1]) << 16);
        u32 hi = (u32)f2bf(s[m][n][2]) | ((u32)f2bf(s[m][n][3]) << 16);
        int byt = ((m * 2 + (n >> 1)) << 10) | (g << 3) | ((c & 3) << 5) |
                  (((c >> 2) & 1) << 9) | ((((n & 1) * 2) + (c >> 3)) << 7);
        uint2 u; u.x = lo; u.y = hi;
        *(uint2*)((char*)pw + byt) = u;
      }

#pragma unroll
    for (int ks = 0; ks < 2; ks++) {
      bfrag8 pa[2];
#pragma unroll
      for (int m = 0; m < 2; m++) {
        union { bfrag8 v; u16 s16[8]; } u;
#pragma unroll
        for (int j = 0; j < 4; j++) {
          int e = ((m * 2 + ks) << 9) + c + j * 16 + g * 64;
          u.s16[j] = pw[e];
          u.s16[4 + j] = pw[e + 256];
        }
        pa[m] = u.v;
      }
#pragma unroll
      for (int n = 0; n < 6; n++) {
        int dv = n * 16 + c;
        int byt = ((dv << 7) + (ks << 6) + (g << 4)) ^ ((dv & 7) << 4);
        bfrag8 vb = *(const bfrag8*)(v_lds + byt);
#pragma unroll
        for (int m = 0; m < 2; m++)
          acc_o[m][n] = __builtin_amdgcn_mfma_f32_16x16x32_bf16(pa[m], vb, acc_o[m][n], 0, 0, 0);
      }
    }

    asm volatile("s_barrier" ::: "memory");
    if (ci + 2 < nc) stage(ci + 2);
  }

#pragma unroll
  for (int m = 0; m < 2; m++) {
    float inv[4];
#pragma unroll
    for (int r = 0; r < 4; r++) inv[r] = 1.0f / l_run[m][r];
#pragma unroll
    for (int n = 0; n < 6; n++)
#pragma unroll
      for (int r = 0; r < 4; r++) {
        int tq = t0 + m * 16 + g * 4 + r;
        attn_out[(size_t)tq * ATTN + h * DVH + n * 16 + c] = f2bf(acc_o[m][n][r] * inv[r]);
      }
  }
}

// ---------------- launcher ----------------
extern "C" void kernel_launch(void* const* d_in, const int* in_sizes, int n_in,
                              void* d_out, int out_size, void* d_ws, size_t ws_size,
                              hipStream_t stream) {
  const int* positions = (const int*)d_in[0];
  const float* hidden = (const float*)d_in[1];
  const float* qkv_w = (const float*)d_in[2];
  const float* o_w = (const float*)d_in[3];
  const float* sink = (const float*)d_in[4];
  char* ws = (char*)d_ws;

  u16* hs_bf   = (u16*)(ws + 0);          // 16,777,216 B (dead after gemm1)
  u16* w1_bf   = (u16*)(ws + 16777216);   // 24,117,248 B (dead after gemm1)
  u16* attn_bf = (u16*)(ws + 0);          // 25,165,824 B (overlaps hs/w1)
  u16* vt_buf  = (u16*)(ws + 25165824);   //  6,291,456 B
  u16* w2_bf   = (u16*)(ws + 40894464);   // 12,582,912 B
  u16* qkv_bf  = (u16*)(ws + 53477376);   // 48,234,496 B

  bool k32Ok = (hipFuncSetAttribute((const void*)&gemm_v3k32<0>,
                  hipFuncAttributeMaxDynamicSharedMemorySize, 73728) == hipSuccess);
  bool v3Ok = (hipFuncSetAttribute((const void*)&gemm_v3<1>,
                  hipFuncAttributeMaxDynamicSharedMemorySize, 147456) == hipSuccess);
  (void)hipFuncSetAttribute((const void*)&attn_mfma,
                            hipFuncAttributeMaxDynamicSharedMemorySize, 73728);

  cvt3_kernel<<<dim3(2048), dim3(256), 0, stream>>>(hidden, qkv_w, o_w,
                                                    hs_bf, w1_bf, w2_bf,
                                                    2097152, 3014656, 1572864);

  if (k32Ok)
    gemm_v3k32<0><<<dim3(736), dim3(512), 73728, stream>>>(hs_bf, w1_bf, (void*)qkv_bf,
                                                           T_SEQ, QKVN, HIDDEN, 16);
  else
    gemm_nt<0><<<dim3(32, 46), dim3(256), 0, stream>>>(hs_bf, w1_bf, (void*)qkv_bf,
                                                       T_SEQ, QKVN, HIDDEN);

  rope_kernel<<<dim3(5120), dim3(256), 0, stream>>>(qkv_bf, positions);
  vt_kernel<<<dim3(T_SEQ / 64, NKVH), dim3(256), 0, stream>>>(qkv_bf, vt_buf);
  attn_mfma<<<dim3(T_SEQ / 32, NKVH), dim3(256), 73728, stream>>>(qkv_bf, vt_buf, sink, attn_bf);

  if (v3Ok)
    gemm_v3<1><<<dim3(256), dim3(512), 147456, stream>>>(attn_bf, w2_bf, d_out,
                                                         T_SEQ, HIDDEN, ATTN, 16);
  else
    gemm_nt<1><<<dim3(32, 16), dim3(256), 0, stream>>>(attn_bf, w2_bf, d_out,
                                                       T_SEQ, HIDDEN, ATTN);
}

// Round 12
// 307.901 us; speedup vs baseline: 1.0436x; 1.0436x over previous
//
#include <hip/hip_runtime.h>
#include <hip/hip_bf16.h>
#include <stdint.h>

#define T_SEQ 4096
#define HIDDEN 2048
#define NQH 32
#define NKVH 8
#define DH 128
#define DVH 96
#define WWIN 512
#define QKVN 5888           // 32*128 + 8*128 + 8*96
#define KOFF 4096
#define VOFF 5120
#define ATTN 3072           // 32*96
#define QSCALE 0.08838834764831845f  // 128^-0.5

typedef uint16_t u16;
typedef uint32_t u32;
typedef __bf16 bfrag8 __attribute__((ext_vector_type(8)));
typedef float f32x4v __attribute__((ext_vector_type(4)));
typedef float f32x16 __attribute__((ext_vector_type(16)));

__device__ __forceinline__ u16 f2bf(float x) {
  u32 u = __float_as_uint(x);
  return (u16)((u + 0x7fffu + ((u >> 16) & 1u)) >> 16);
}
__device__ __forceinline__ float bf2f(u16 v) { return __uint_as_float(((u32)v) << 16); }

__device__ __forceinline__ void gload16(const u16* src, char* ldst) {
  __builtin_amdgcn_global_load_lds((const __attribute__((address_space(1))) u32*)src,
                                   (__attribute__((address_space(3))) u32*)ldst, 16, 0, 0);
}

// ---------------- merged f32 -> bf16 convert (3 buffers, 1 launch) --------
__global__ void cvt3_kernel(const float* __restrict__ i1, const float* __restrict__ i2,
                            const float* __restrict__ i3,
                            u16* __restrict__ o1, u16* __restrict__ o2, u16* __restrict__ o3,
                            int n1, int n2, int n3) {
  int i = blockIdx.x * blockDim.x + threadIdx.x;
  int st = gridDim.x * blockDim.x;
  int total = n1 + n2 + n3;
  for (; i < total; i += st) {
    const float4* src;
    ushort4* dst;
    int j;
    if (i < n1) { src = (const float4*)i1; dst = (ushort4*)o1; j = i; }
    else if (i < n1 + n2) { src = (const float4*)i2; dst = (ushort4*)o2; j = i - n1; }
    else { src = (const float4*)i3; dst = (ushort4*)o3; j = i - n1 - n2; }
    float4 v = src[j];
    ushort4 o;
    o.x = f2bf(v.x); o.y = f2bf(v.y); o.z = f2bf(v.z); o.w = f2bf(v.w);
    dst[j] = o;
  }
}

// =======================================================================
// GEMM core v3 (round-5 proven): C[M][N] = A[M][K] * B[N][K]^T
// BM=256 BN=128 BK=64, 8 waves 4Mx2N (64x64/wave), 32x32x16 MFMA,
// triple-buffered LDS, counted vmcnt(6), 1 barrier/tile.
// GEMM line closed (r12): BK=32 2-blocks/CU regressed (bank conflicts 3x),
// 256^2 tiles lose to pack quantization (N=5888=2^8*23). This config is
// the measured best: ~800 TF on gemm1@736, ~805 TF on gemm2@256.
// =======================================================================
template<int OUT_F32>
__global__ __launch_bounds__(512, 2) void gemm_v3(const u16* __restrict__ A,
                                                  const u16* __restrict__ B,
                                                  void* __restrict__ Cp,
                                                  int M, int N, int K, int nbm) {
  extern __shared__ char lds[];   // 3 x 49152 B
  const int tid = threadIdx.x;
  const int w = tid >> 6, lane = tid & 63;
  const int wr = w >> 1, wc = w & 1;
  const int r5 = lane & 31, kg = lane >> 5;

  const int nwg = gridDim.x;
  int bid = (int)blockIdx.x;
  if ((nwg & 7) == 0) bid = (bid & 7) * (nwg >> 3) + (bid >> 3);
  const int bm = (bid % nbm) * 256;
  const int bn = (bid / nbm) * 128;
  const int NT = K >> 6;

  f32x16 acc[2][2];
#pragma unroll
  for (int mb = 0; mb < 2; mb++)
#pragma unroll
    for (int nb = 0; nb < 2; nb++)
#pragma unroll
      for (int i = 0; i < 16; i++) acc[mb][nb][i] = 0.f;

  const int q = r5 * 128 + ((kg ^ (r5 & 7)) << 4);

  auto stageA = [&](int t) {
    char* dst = lds + (t % 3) * 49152;
    const u16* Abase = A + (size_t)bm * K + ((size_t)t << 6);
#pragma unroll
    for (int i = 0; i < 4; i++) {
      int D = (w * 4 + i) * 1024 + lane * 16;
      int row = D >> 7;
      int kb = (D ^ ((row & 7) << 4)) & 127;
      gload16(Abase + (size_t)row * K + (kb >> 1), dst + D);
    }
  };
  auto stageB = [&](int t) {
    char* dst = lds + (t % 3) * 49152 + 32768;
    const u16* Bbase = B + (size_t)bn * K + ((size_t)t << 6);
#pragma unroll
    for (int i = 0; i < 2; i++) {
      int D = (w * 2 + i) * 1024 + lane * 16;
      int row = D >> 7;
      int kb = (D ^ ((row & 7) << 4)) & 127;
      gload16(Bbase + (size_t)row * K + (kb >> 1), dst + D);
    }
  };

  stageA(0); stageB(0);

  for (int t = 0; t < NT; ++t) {
    const char* Ab = lds + (t % 3) * 49152 + wr * 8192;
    const char* Bb = lds + (t % 3) * 49152 + 32768 + wc * 8192;
    if (t + 1 < NT) {
      stageA(t + 1);
      stageB(t + 1);
      asm volatile("s_waitcnt vmcnt(6)");
    } else {
      asm volatile("s_waitcnt vmcnt(0)");
    }
    asm volatile("s_barrier" ::: "memory");

    bfrag8 af[2][2], bf[2][2];
#pragma unroll
    for (int ks = 0; ks < 2; ks++) {
#pragma unroll
      for (int mb = 0; mb < 2; mb++)
        af[mb][ks] = *(const bfrag8*)(Ab + mb * 4096 + (q ^ (ks << 5)));
#pragma unroll
      for (int nb = 0; nb < 2; nb++)
        bf[nb][ks] = *(const bfrag8*)(Bb + nb * 4096 + (q ^ (ks << 5)));
    }
    __builtin_amdgcn_s_setprio(1);
#pragma unroll
    for (int ks = 0; ks < 2; ks++)
#pragma unroll
      for (int mb = 0; mb < 2; mb++)
#pragma unroll
        for (int nb = 0; nb < 2; nb++)
          acc[mb][nb] = __builtin_amdgcn_mfma_f32_32x32x16_bf16(af[mb][ks], bf[nb][ks], acc[mb][nb], 0, 0, 0);
    __builtin_amdgcn_s_setprio(0);

    bfrag8 af2[2][2], bf2[2][2];
#pragma unroll
    for (int ks = 0; ks < 2; ks++) {
#pragma unroll
      for (int mb = 0; mb < 2; mb++)
        af2[mb][ks] = *(const bfrag8*)(Ab + mb * 4096 + (q ^ ((ks + 2) << 5)));
#pragma unroll
      for (int nb = 0; nb < 2; nb++)
        bf2[nb][ks] = *(const bfrag8*)(Bb + nb * 4096 + (q ^ ((ks + 2) << 5)));
    }
    __builtin_amdgcn_s_setprio(1);
#pragma unroll
    for (int ks = 0; ks < 2; ks++)
#pragma unroll
      for (int mb = 0; mb < 2; mb++)
#pragma unroll
        for (int nb = 0; nb < 2; nb++)
          acc[mb][nb] = __builtin_amdgcn_mfma_f32_32x32x16_bf16(af2[mb][ks], bf2[nb][ks], acc[mb][nb], 0, 0, 0);
    __builtin_amdgcn_s_setprio(0);
  }

  const int rb0 = bm + wr * 64;
  const int cb0 = bn + wc * 64;
#pragma unroll
  for (int mb = 0; mb < 2; mb++)
#pragma unroll
    for (int nb = 0; nb < 2; nb++)
#pragma unroll
      for (int i = 0; i < 16; i++) {
        int rowl = (i & 3) + 8 * (i >> 2) + 4 * kg;
        size_t off = (size_t)(rb0 + mb * 32 + rowl) * N + cb0 + nb * 32 + r5;
        if (OUT_F32) ((float*)Cp)[off] = acc[mb][nb][i];
        else         ((u16*)Cp)[off] = f2bf(acc[mb][nb][i]);
      }
}

// ---------------- fallback bf16 NT GEMM (round-2 proven) ----------------
template<int OUT_F32>
__global__ __launch_bounds__(256) void gemm_nt(const u16* __restrict__ A,
                                               const u16* __restrict__ B,
                                               void* __restrict__ Cp,
                                               int M, int N, int K) {
  __shared__ u16 Asm[128 * 32];
  __shared__ u16 Bsm[128 * 32];
  const int tid = threadIdx.x;
  const int wv = tid >> 6, lane = tid & 63;
  const int bm = blockIdx.x * 128, bn = blockIdx.y * 128;
  const int wm = (wv >> 1) * 64, wn = (wv & 1) * 64;
  const int srow = lane >> 2;
  const int scol = (lane & 3) * 8;
  const int fr = lane & 15, fk = (lane >> 4) * 8;
  f32x4v acc[4][4];
#pragma unroll
  for (int i = 0; i < 4; i++)
#pragma unroll
    for (int j = 0; j < 4; j++) acc[i][j] = {0.f, 0.f, 0.f, 0.f};

  for (int kt = 0; kt < K; kt += 32) {
    __syncthreads();
#pragma unroll
    for (int c = 0; c < 2; c++) {
      const int ci = wv * 2 + c;
      const u16* ga = A + (size_t)(bm + ci * 16 + srow) * K + kt + scol;
      const u16* gb = B + (size_t)(bn + ci * 16 + srow) * K + kt + scol;
      gload16(ga, (char*)(Asm + ci * 512));
      gload16(gb, (char*)(Bsm + ci * 512));
    }
    __syncthreads();
    bfrag8 af[4], bf[4];
#pragma unroll
    for (int i = 0; i < 4; i++) af[i] = *(const bfrag8*)(Asm + (wm + i * 16 + fr) * 32 + fk);
#pragma unroll
    for (int j = 0; j < 4; j++) bf[j] = *(const bfrag8*)(Bsm + (wn + j * 16 + fr) * 32 + fk);
#pragma unroll
    for (int i = 0; i < 4; i++)
#pragma unroll
      for (int j = 0; j < 4; j++)
        acc[i][j] = __builtin_amdgcn_mfma_f32_16x16x32_bf16(af[i], bf[j], acc[i][j], 0, 0, 0);
  }
  const int orow = (lane >> 4) * 4, ocol = lane & 15;
#pragma unroll
  for (int i = 0; i < 4; i++)
#pragma unroll
    for (int j = 0; j < 4; j++) {
      size_t base = (size_t)(bm + wm + i * 16 + orow) * N + (size_t)(bn + wn + j * 16 + ocol);
#pragma unroll
      for (int r = 0; r < 4; r++) {
        if (OUT_F32) ((float*)Cp)[base + (size_t)r * N] = acc[i][j][r];
        else         ((u16*)Cp)[base + (size_t)r * N] = f2bf(acc[i][j][r]);
      }
    }
}

// ---------------- RoPE in-place on q,k — uint4-vectorized (8 d/thread) ----
__global__ void rope_kernel(u16* __restrict__ qkv, const int* __restrict__ pos) {
  int gid = blockIdx.x * 256 + threadIdx.x;   // 4096*40*8 threads
  int dc = gid & 7;
  int r = gid >> 3;
  int hh = r % 40;
  int t = r / 40;
  if (t >= T_SEQ) return;
  int off = (hh < 32) ? hh * 128 : KOFF + (hh - 32) * 128;
  u16* p = qkv + (size_t)t * QKVN + off + dc * 8;
  uint4 a = *(const uint4*)p;
  uint4 b = *(const uint4*)(p + 64);
  const u32* aw = (const u32*)&a;
  const u32* bw = (const u32*)&b;
  float pt = (float)pos[t];
  float sc = (hh < 32) ? QSCALE : 1.0f;
  union { uint4 v; u16 s[8]; } ra, rb;
#pragma unroll
  for (int j = 0; j < 8; j++) {
    int d = dc * 8 + j;
    float inv_freq = exp2f(-(float)d * 0.3114307588956852f);
    float ang = pt * inv_freq;
    float cs = cosf(ang), sn = sinf(ang);
    float x1 = bf2f((u16)(aw[j >> 1] >> ((j & 1) * 16)));
    float x2 = bf2f((u16)(bw[j >> 1] >> ((j & 1) * 16)));
    ra.s[j] = f2bf((x1 * cs - x2 * sn) * sc);
    rb.s[j] = f2bf((x2 * cs + x1 * sn) * sc);
  }
  *(uint4*)p = ra.v;
  *(uint4*)(p + 64) = rb.v;
}

// ---------------- V transpose: qkv V region -> vt[hk][dv][t] ----------------
__global__ __launch_bounds__(256) void vt_kernel(const u16* __restrict__ qkv,
                                                 u16* __restrict__ vt) {
  __shared__ u16 tile[64][100];
  const int t0 = blockIdx.x * 64;
  const int hk = blockIdx.y;
  const int tid = threadIdx.x;
#pragma unroll
  for (int i = 0; i < 3; i++) {
    int idx = i * 256 + tid;
    int row = idx / 12, ch = idx % 12;
    const u16* g = qkv + (size_t)(t0 + row) * QKVN + VOFF + hk * DVH + ch * 8;
    uint2 a = *(const uint2*)g;
    uint2 b = *(const uint2*)(g + 4);
    *(uint2*)&tile[row][ch * 8] = a;
    *(uint2*)&tile[row][ch * 8 + 4] = b;
  }
  __syncthreads();
#pragma unroll
  for (int i = 0; i < 3; i++) {
    int idx = i * 256 + tid;
    int dv = idx >> 3, tc = (idx & 7) * 8;
    union { uint4 v4; u16 s[8]; } o;
#pragma unroll
    for (int j = 0; j < 8; j++) o.s[j] = tile[tc + j][dv];
    *(uint4*)(vt + (((size_t)(hk * 96 + dv)) << 12) + t0 + tc) = o.v4;
  }
}

// =======================================================================
// MFMA sliding-window attention with sink — r7/r10-proven QBLK=32.
// Double-buffered staging, counted vmcnt(7), raw barriers, exact
// rescale-skip. Per-wave VGPR stays under the 2-wave/SIMD budget
// (QBLK=64 per-wave spills — r9). LDS 72 KB dynamic.
// =======================================================================
__global__ __launch_bounds__(256, 2) void attn_mfma(const u16* __restrict__ qkv,
                                                    const u16* __restrict__ vt,
                                                    const float* __restrict__ sink_bias,
                                                    u16* __restrict__ attn_out) {
  extern __shared__ char smem[];

  const int tid = threadIdx.x;
  const int wv = tid >> 6;
  const int lane = tid & 63;
  const int g = lane >> 4;
  const int c = lane & 15;
  const int t0 = blockIdx.x * 32;
  const int hk = blockIdx.y;
  const int h = hk * 4 + wv;
  u16* pw = (u16*)(smem + 57344 + wv * 4096);

  bfrag8 qf[2][4];
#pragma unroll
  for (int m = 0; m < 2; m++)
#pragma unroll
    for (int kf = 0; kf < 4; kf++)
      qf[m][kf] = *(const bfrag8*)(qkv + (size_t)(t0 + m * 16 + c) * QKVN + h * DH + kf * 32 + g * 8);

  f32x4v acc_o[2][6];
#pragma unroll
  for (int m = 0; m < 2; m++)
#pragma unroll
    for (int n = 0; n < 6; n++) acc_o[m][n] = {0.f, 0.f, 0.f, 0.f};

  const float sb = sink_bias[h];
  float m_run[2][4], l_run[2][4];
#pragma unroll
  for (int m = 0; m < 2; m++)
#pragma unroll
    for (int r = 0; r < 4; r++) { m_run[m][r] = sb; l_run[m][r] = 1.0f; }

  int cb0 = t0 - (WWIN - 1);
  cb0 = (cb0 < 0) ? 0 : (cb0 & ~63);
  const int nc = (t0 + 32 - cb0 + 63) >> 6;

  auto stage = [&](int ci) {
    const int cb = cb0 + ci * 64;
    char* kd = smem + (ci & 1) * 16384;
    char* vd = smem + 32768 + (ci & 1) * 12288;
#pragma unroll
    for (int it = 0; it < 4; it++) {
      int dest = it * 4096 + tid * 16;
      int row = dest >> 8;
      int src = dest ^ ((row & 7) << 4);
      gload16(qkv + (size_t)(cb + row) * QKVN + KOFF + hk * DH + ((src & 255) >> 1), kd + dest);
    }
#pragma unroll
    for (int it = 0; it < 3; it++) {
      int dest = it * 4096 + tid * 16;
      int row = dest >> 7;
      int src = dest ^ ((row & 7) << 4);
      gload16(vt + (((size_t)(hk * 96 + row)) << 12) + cb + ((src & 127) >> 1), vd + dest);
    }
  };

  stage(0);
  if (nc > 1) stage(1);

  for (int ci = 0; ci < nc; ci++) {
    const int cb = cb0 + ci * 64;
    const char* k_lds = smem + (ci & 1) * 16384;
    const char* v_lds = smem + 32768 + (ci & 1) * 12288;
    if (ci + 1 < nc) asm volatile("s_waitcnt vmcnt(7)");
    else             asm volatile("s_waitcnt vmcnt(0)");
    asm volatile("s_barrier" ::: "memory");

    f32x4v s[2][4];
#pragma unroll
    for (int m = 0; m < 2; m++)
#pragma unroll
      for (int n = 0; n < 4; n++) s[m][n] = {0.f, 0.f, 0.f, 0.f};
#pragma unroll
    for (int kf = 0; kf < 4; kf++) {
      bfrag8 kb[4];
#pragma unroll
      for (int n = 0; n < 4; n++) {
        int key = n * 16 + c;
        int byt = ((key << 8) + (kf << 6) + (g << 4)) ^ ((key & 7) << 4);
        kb[n] = *(const bfrag8*)(k_lds + byt);
      }
#pragma unroll
      for (int m = 0; m < 2; m++)
#pragma unroll
        for (int n = 0; n < 4; n++)
          s[m][n] = __builtin_amdgcn_mfma_f32_16x16x32_bf16(qf[m][kf], kb[n], s[m][n], 0, 0, 0);
    }

    if ((cb + 63 > t0) || (cb + WWIN < t0 + 32)) {
#pragma unroll
      for (int m = 0; m < 2; m++)
#pragma unroll
        for (int n = 0; n < 4; n++)
#pragma unroll
          for (int r = 0; r < 4; r++) {
            int rel = (t0 + m * 16 + g * 4 + r) - (cb + n * 16 + c);
            if (!(rel >= 0 && rel < WWIN)) s[m][n][r] = -3.0e38f;
          }
    }

    float corr[2][4];
    bool grew = false;
#pragma unroll
    for (int m = 0; m < 2; m++)
#pragma unroll
      for (int r = 0; r < 4; r++) {
        float v0 = fmaxf(fmaxf(s[m][0][r], s[m][1][r]), fmaxf(s[m][2][r], s[m][3][r]));
        v0 = fmaxf(v0, __shfl_xor(v0, 1));
        v0 = fmaxf(v0, __shfl_xor(v0, 2));
        v0 = fmaxf(v0, __shfl_xor(v0, 4));
        v0 = fmaxf(v0, __shfl_xor(v0, 8));
        float mo = m_run[m][r];
        float mn = fmaxf(mo, v0);
        corr[m][r] = __expf(mo - mn);
        grew |= (mn > mo);
        m_run[m][r] = mn;
        float p0 = __expf(s[m][0][r] - mn);
        float p1 = __expf(s[m][1][r] - mn);
        float p2 = __expf(s[m][2][r] - mn);
        float p3 = __expf(s[m][3][r] - mn);
        s[m][0][r] = p0; s[m][1][r] = p1; s[m][2][r] = p2; s[m][3][r] = p3;
        float rs = p0 + p1 + p2 + p3;
        rs += __shfl_xor(rs, 1);
        rs += __shfl_xor(rs, 2);
        rs += __shfl_xor(rs, 4);
        rs += __shfl_xor(rs, 8);
        l_run[m][r] = l_run[m][r] * corr[m][r] + rs;
      }
    if (__any(grew)) {   // exact: when corr==1 for all rows the rescale is a no-op
#pragma unroll
      for (int m = 0; m < 2; m++)
#pragma unroll
        for (int n = 0; n < 6; n++)
#pragma unroll
        for (int r = 0; r < 4; r++) acc_o[m][n][r] *= corr[m][r];
    }

#pragma unroll
    for (int m = 0; m < 2; m++)
#pragma unroll
      for (int n = 0; n < 4; n++) {
        u32 lo = (u32)f2bf(s[m][n][0]) | ((u32)f2bf(s[m][n][1]) << 16);
        u32 hi = (u32)f2bf(s[m][n][2]) | ((u32)f2bf(s[m][n][3]) << 16);
        int byt = ((m * 2 + (n >> 1)) << 10) | (g << 3) | ((c & 3) << 5) |
                  (((c >> 2) & 1) << 9) | ((((n & 1) * 2) + (c >> 3)) << 7);
        uint2 u; u.x = lo; u.y = hi;
        *(uint2*)((char*)pw + byt) = u;
      }

#pragma unroll
    for (int ks = 0; ks < 2; ks++) {
      bfrag8 pa[2];
#pragma unroll
      for (int m = 0; m < 2; m++) {
        union { bfrag8 v; u16 s16[8]; } u;
#pragma unroll
        for (int j = 0; j < 4; j++) {
          int e = ((m * 2 + ks) << 9) + c + j * 16 + g * 64;
          u.s16[j] = pw[e];
          u.s16[4 + j] = pw[e + 256];
        }
        pa[m] = u.v;
      }
#pragma unroll
      for (int n = 0; n < 6; n++) {
        int dv = n * 16 + c;
        int byt = ((dv << 7) + (ks << 6) + (g << 4)) ^ ((dv & 7) << 4);
        bfrag8 vb = *(const bfrag8*)(v_lds + byt);
#pragma unroll
        for (int m = 0; m < 2; m++)
          acc_o[m][n] = __builtin_amdgcn_mfma_f32_16x16x32_bf16(pa[m], vb, acc_o[m][n], 0, 0, 0);
      }
    }

    asm volatile("s_barrier" ::: "memory");
    if (ci + 2 < nc) stage(ci + 2);
  }

#pragma unroll
  for (int m = 0; m < 2; m++) {
    float inv[4];
#pragma unroll
    for (int r = 0; r < 4; r++) inv[r] = 1.0f / l_run[m][r];
#pragma unroll
    for (int n = 0; n < 6; n++)
#pragma unroll
      for (int r = 0; r < 4; r++) {
        int tq = t0 + m * 16 + g * 4 + r;
        attn_out[(size_t)tq * ATTN + h * DVH + n * 16 + c] = f2bf(acc_o[m][n][r] * inv[r]);
      }
  }
}

// ---------------- launcher ----------------
extern "C" void kernel_launch(void* const* d_in, const int* in_sizes, int n_in,
                              void* d_out, int out_size, void* d_ws, size_t ws_size,
                              hipStream_t stream) {
  const int* positions = (const int*)d_in[0];
  const float* hidden = (const float*)d_in[1];
  const float* qkv_w = (const float*)d_in[2];
  const float* o_w = (const float*)d_in[3];
  const float* sink = (const float*)d_in[4];
  char* ws = (char*)d_ws;

  u16* hs_bf   = (u16*)(ws + 0);          // 16,777,216 B (dead after gemm1)
  u16* w1_bf   = (u16*)(ws + 16777216);   // 24,117,248 B (dead after gemm1)
  u16* attn_bf = (u16*)(ws + 0);          // 25,165,824 B (overlaps hs/w1)
  u16* vt_buf  = (u16*)(ws + 25165824);   //  6,291,456 B
  u16* w2_bf   = (u16*)(ws + 40894464);   // 12,582,912 B
  u16* qkv_bf  = (u16*)(ws + 53477376);   // 48,234,496 B

  bool v3Ok =
    (hipFuncSetAttribute((const void*)&gemm_v3<0>,
                         hipFuncAttributeMaxDynamicSharedMemorySize, 147456) == hipSuccess) &&
    (hipFuncSetAttribute((const void*)&gemm_v3<1>,
                         hipFuncAttributeMaxDynamicSharedMemorySize, 147456) == hipSuccess);
  (void)hipFuncSetAttribute((const void*)&attn_mfma,
                            hipFuncAttributeMaxDynamicSharedMemorySize, 73728);

  cvt3_kernel<<<dim3(2048), dim3(256), 0, stream>>>(hidden, qkv_w, o_w,
                                                    hs_bf, w1_bf, w2_bf,
                                                    2097152, 3014656, 1572864);

  if (v3Ok)
    gemm_v3<0><<<dim3(736), dim3(512), 147456, stream>>>(hs_bf, w1_bf, (void*)qkv_bf,
                                                         T_SEQ, QKVN, HIDDEN, 16);
  else
    gemm_nt<0><<<dim3(32, 46), dim3(256), 0, stream>>>(hs_bf, w1_bf, (void*)qkv_bf,
                                                       T_SEQ, QKVN, HIDDEN);

  rope_kernel<<<dim3(5120), dim3(256), 0, stream>>>(qkv_bf, positions);
  vt_kernel<<<dim3(T_SEQ / 64, NKVH), dim3(256), 0, stream>>>(qkv_bf, vt_buf);
  attn_mfma<<<dim3(T_SEQ / 32, NKVH), dim3(256), 73728, stream>>>(qkv_bf, vt_buf, sink, attn_bf);

  if (v3Ok)
    gemm_v3<1><<<dim3(256), dim3(512), 147456, stream>>>(attn_bf, w2_bf, d_out,
                                                         T_SEQ, HIDDEN, ATTN, 16);
  else
    gemm_nt<1><<<dim3(32, 16), dim3(256), 0, stream>>>(attn_bf, w2_bf, d_out,
                                                       T_SEQ, HIDDEN, ATTN);
}